// Round 23
// baseline (772.340 us; speedup 1.0000x reference)
//
#include <hip/hip_runtime.h>

#define Vv 32000
#define Ee 256
#define Hh 512
#define Ll 128
#define Bb 16
#define Tt 128
#define G3 1536   // 3*H
#define NSW 256   // scan WGs: 16 groups x 16 WGs
#define NPAIRB (Bb * Hh)  // pairs per buffer
#define NLOG 500  // gated logits WGs (64-col n-blocks)

typedef __attribute__((ext_vector_type(8))) short short8;
typedef __attribute__((ext_vector_type(4))) float f32x4;

__device__ __forceinline__ float sigmoidf_(float x) { return 1.f / (1.f + __expf(-x)); }

__device__ __forceinline__ unsigned short f2bf(float f) {
  unsigned int u = __float_as_uint(f);
  u = (u + 0x7fffu + ((u >> 16) & 1u)) >> 16;
  return (unsigned short)u;
}

// ---------------- prep kernel: cvt + zero_first + pair-zero + gcnt-zero + transposes ----
__device__ __forceinline__ void transpose_body(int b, const float* __restrict__ in,
                                               float* __restrict__ outp) {
  __shared__ float tile[32][33];
  int bx = b & 7, by = b >> 3;           // grid (8, 48) flattened
  int tx = threadIdx.x & 31, ty = threadIdx.x >> 5;
  int c = bx * 32 + tx;
  int r0 = by * 32;
  for (int i = ty; i < 32; i += 8)
    tile[i][tx] = in[(size_t)(r0 + i) * 256 + c];
  __syncthreads();
  int r = r0 + tx;
  int c0 = bx * 32;
  for (int i = ty; i < 32; i += 8)
    outp[(size_t)(c0 + i) * 1536 + r] = tile[tx][i];
}

__global__ void __launch_bounds__(256) k_prep(
    const float* __restrict__ cvt_in, unsigned short* __restrict__ cvt_out, int ncvt,
    float* __restrict__ out, uint2* __restrict__ pairs0, int* __restrict__ gcnt,
    const float* __restrict__ encWih, float* __restrict__ wihT_e,
    const float* __restrict__ decWih, float* __restrict__ wihT_d) {
  int bid = blockIdx.x;
  const int tid = threadIdx.x;
  if (bid < ncvt) {
    int i = bid * 256 + tid;
    float4 v = ((const float4*)cvt_in)[i];
    ushort4 o;
    o.x = f2bf(v.x); o.y = f2bf(v.y); o.z = f2bf(v.z); o.w = f2bf(v.w);
    ((ushort4*)cvt_out)[i] = o;
    return;
  }
  bid -= ncvt;
  if (bid < 2000) {              // zero out[:,0,:]
    int idx = bid * 256 + tid;
    int b = idx / Vv, v = idx % Vv;
    out[(size_t)b * Tt * Vv + v] = 0.f;
    return;
  }
  bid -= 2000;
  if (bid < 64) {                // zero 256 KB of pair buffers
    uint4 z = make_uint4(0u, 0u, 0u, 0u);
    ((uint4*)pairs0)[bid * 256 + tid] = z;
    return;
  }
  bid -= 64;
  if (bid < 1) {                 // zero gcnt (16 lines x 64 ints)
    uint4 z = make_uint4(0u, 0u, 0u, 0u);
    ((uint4*)gcnt)[tid] = z;
    return;
  }
  bid -= 1;
  if (bid < 384) transpose_body(bid, encWih, wihT_e);
  else transpose_body(bid - 384, decWih, wihT_d);
}

// ---------------- gx body ----------------
__device__ __forceinline__ void gx_body(int e, const int* __restrict__ x,
                                        const float* __restrict__ emb,
                                        const float* __restrict__ WihT,
                                        const float* __restrict__ b_ih,
                                        float* __restrict__ gx) {
  __shared__ float A[16][Ee];
  int mt = e / 6, gy = e % 6;
  int g = gy * 256 + threadIdx.x;
  for (int i = 0; i < 16; i++) {
    int tok = x[i * Tt + mt];
    A[i][threadIdx.x] = emb[(size_t)tok * Ee + threadIdx.x];
  }
  __syncthreads();
  float acc[16];
  float bg = b_ih[g];
#pragma unroll
  for (int i = 0; i < 16; i++) acc[i] = bg;
#pragma unroll 4
  for (int ee = 0; ee < Ee; ee++) {
    float w = WihT[(size_t)ee * G3 + g];
#pragma unroll
    for (int i = 0; i < 16; i++) acc[i] = fmaf(A[i][ee], w, acc[i]);
  }
#pragma unroll
  for (int i = 0; i < 16; i++)
    gx[(size_t)(mt * 16 + i) * G3 + g] = acc[i];
}

__global__ void k_gx(const int* __restrict__ x, const float* __restrict__ emb,
                     const float* __restrict__ WihT, const float* __restrict__ b_ih,
                     float* __restrict__ gx) {
  gx_body(blockIdx.x, x, emb, WihT, b_ih, gx);
}

// ---------------- scan body: data-is-flag pair exchange (r14 proven) ----------------
// HSEQ (decoder): hseq stores sc1 (LLC-visible within fused kernel); per-step gcnt add.
template <bool HSEQ>
__device__ __forceinline__ void scan_body(
    const float* __restrict__ Whh, const float* __restrict__ bhh,
    const float* __restrict__ gx, uint2* __restrict__ pairs,
    unsigned short* __restrict__ hseq, int nsteps,
    float* __restrict__ h_lds, int* __restrict__ gcnt) {
  const int tid = threadIdx.x;
  const int wg = blockIdx.x;
  const int g = wg >> 4;
  const int wgl = wg & 15;
  const int wave = tid >> 6;
  const int lane = tid & 63;
  const int cl = lane >> 3;    // 0..7
  const int ks = lane & 7;     // 0..7
  const int j = wgl * 32 + wave * 8 + cl;
  const bool gate = (ks == 0);

  // weights: 3 gates x 64 interleaved k in f32 regs
  float wr[64], wz[64], wn[64];
  {
    const float* R = Whh + (size_t)j * Hh + ks * 4;
    const float* Z = R + (size_t)Hh * Hh;
    const float* N = Z + (size_t)Hh * Hh;
#pragma unroll
    for (int q = 0; q < 16; ++q) {
      float4 a = *(const float4*)(R + q * 32);
      float4 b = *(const float4*)(Z + q * 32);
      float4 c = *(const float4*)(N + q * 32);
      wr[4*q] = a.x; wr[4*q+1] = a.y; wr[4*q+2] = a.z; wr[4*q+3] = a.w;
      wz[4*q] = b.x; wz[4*q+1] = b.y; wz[4*q+2] = b.z; wz[4*q+3] = b.w;
      wn[4*q] = c.x; wn[4*q+1] = c.y; wn[4*q+2] = c.z; wn[4*q+3] = c.w;
    }
  }
  float bhr = 0.f, bhz = 0.f, bhn = 0.f;
  if (gate) { bhr = bhh[j]; bhz = bhh[Hh + j]; bhn = bhh[2 * Hh + j]; }

  float xr = 0.f, xz = 0.f, xn = 0.f;
  if (gate) {
    const float* gp = gx + (size_t)g * G3 + j;
    xr = gp[0]; xz = gp[Hh]; xn = gp[2 * Hh];
  }

  for (int t = 0; t < nsteps; ++t) {
    // ---- poll + stage h(t): data IS the flag (one LLC RT) ----
    {
      const uint4* pp =
          (const uint4*)(pairs + (size_t)(t & 1) * NPAIRB + (size_t)g * Hh) + tid;
      const unsigned ep = (unsigned)t;
      uint4 v;
      for (int it = 0; it < 200000; ++it) {
        asm volatile("global_load_dwordx4 %0, %1, off sc1\n\ts_waitcnt vmcnt(0)"
                     : "=v"(v) : "v"(pp) : "memory");
        if (v.y == ep && v.w == ep) break;
      }
      *(float2*)&h_lds[2 * tid] =
          make_float2(__uint_as_float(v.x), __uint_as_float(v.z));
    }
    __syncthreads();

    // ---- per-lane partial dots (reg weights x LDS h broadcast) ----
    float aR = 0.f, aZ = 0.f, aN = 0.f;
    {
      const float* hb = h_lds + ks * 4;
#pragma unroll
      for (int q = 0; q < 16; ++q) {
        float4 hv = *(const float4*)(hb + q * 32);
        aR = fmaf(wr[4*q+0], hv.x, aR);
        aR = fmaf(wr[4*q+1], hv.y, aR);
        aR = fmaf(wr[4*q+2], hv.z, aR);
        aR = fmaf(wr[4*q+3], hv.w, aR);
        aZ = fmaf(wz[4*q+0], hv.x, aZ);
        aZ = fmaf(wz[4*q+1], hv.y, aZ);
        aZ = fmaf(wz[4*q+2], hv.z, aZ);
        aZ = fmaf(wz[4*q+3], hv.w, aZ);
        aN = fmaf(wn[4*q+0], hv.x, aN);
        aN = fmaf(wn[4*q+1], hv.y, aN);
        aN = fmaf(wn[4*q+2], hv.z, aN);
        aN = fmaf(wn[4*q+3], hv.w, aN);
      }
    }
    aR += __shfl_xor(aR, 1, 64); aR += __shfl_xor(aR, 2, 64); aR += __shfl_xor(aR, 4, 64);
    aZ += __shfl_xor(aZ, 1, 64); aZ += __shfl_xor(aZ, 2, 64); aZ += __shfl_xor(aZ, 4, 64);
    aN += __shfl_xor(aN, 1, 64); aN += __shfl_xor(aN, 2, 64); aN += __shfl_xor(aN, 4, 64);

    if (gate) {
      float r = sigmoidf_(xr + aR + bhr);
      float u = sigmoidf_(xz + aZ + bhz);
      float n = tanhf(xn + r * (aN + bhn));
      float hold = h_lds[j];
      float hnew = (1.f - u) * n + u * hold;
      uint2 pv = make_uint2(__float_as_uint(hnew), (unsigned)(t + 1));
      uint2* dst = pairs + (size_t)((t + 1) & 1) * NPAIRB + (size_t)g * Hh + j;
      asm volatile("global_store_dwordx2 %0, %1, off sc1" : : "v"(dst), "v"(pv) : "memory");
      if (HSEQ) {
        unsigned short* hp = hseq + ((size_t)t * Bb + g) * Hh + j;
        int hv = (int)f2bf(hnew);
        asm volatile("global_store_short %0, %1, off sc1" : : "v"(hp), "v"(hv) : "memory");
      }
      if (t + 1 < nsteps) {
        const float* gp = gx + (size_t)((t + 1) * Bb + g) * G3 + j;
        xr = gp[0]; xz = gp[Hh]; xn = gp[2 * Hh];
      }
    }
    // per-step progress: one relaxed agent add per WG (off critical path)
    if (HSEQ && tid == 0)
      __hip_atomic_fetch_add(gcnt + g * 64, 1, __ATOMIC_RELAXED, __HIP_MEMORY_SCOPE_AGENT);
    __syncthreads();   // protect h_lds before next staging overwrite
  }
  if (HSEQ) {
    asm volatile("s_waitcnt vmcnt(0)" ::: "memory");  // last step's stores at LLC
    if (tid == 0)
      __hip_atomic_fetch_add(gcnt + g * 64, 1, __ATOMIC_RELAXED, __HIP_MEMORY_SCOPE_AGENT);
  }
}

// ---------------- fused enc kernel: scan + decoder gx ----------------
__global__ void __launch_bounds__(256, 1) k_enc_fused(
    const float* __restrict__ Whh, const float* __restrict__ bhh,
    const float* __restrict__ gx_e, uint2* __restrict__ pairs,
    const int* __restrict__ x, const float* __restrict__ dec_emb,
    const float* __restrict__ wihT_d, const float* __restrict__ dec_bih,
    float* __restrict__ gx_d) {
  __shared__ float h_lds_e[Hh];
  if (blockIdx.x < NSW)
    scan_body<false>(Whh, bhh, gx_e, pairs, (unsigned short*)nullptr, Tt,
                     h_lds_e, (int*)nullptr);
  else
    gx_body(blockIdx.x - NSW, x, dec_emb, wihT_d, dec_bih, gx_d);
}

// ---------------- gated logits body (runs under the dec scan) ----------------
// WG owns 64-col n-block nb. 8 passes x 256 m rows; pass p gated on all groups'
// gcnt >= 16*E+15 with E = 16p+17 (hseq rows t<=16p+15 then LLC-visible).
// W staged per pass in two 32KB K-halves (LDS budget for co-residency).
template <bool BF16W>
__device__ __forceinline__ void logits_gated(
    int nb, const unsigned short* __restrict__ hseq,
    const unsigned short* __restrict__ Wbf, const float* __restrict__ Wf,
    const float* __restrict__ bias, const int* __restrict__ gcnt,
    float* __restrict__ out, short* __restrict__ W_lds /*16384 shorts*/) {
  const int tid = threadIdx.x;
  const int wave = tid >> 6, lane = tid & 63;
  const int ln = lane & 15, hi = lane >> 4;
  const int n0 = nb * 64;

  f32x4 bv[4];
#pragma unroll
  for (int ni = 0; ni < 4; ++ni)
    bv[ni] = *(const f32x4*)&bias[n0 + ni * 16 + hi * 4];

  for (int pass = 0; pass < 8; ++pass) {
    // ---- gate: every group's aggregate step-count past threshold ----
    const int thr = (pass == 7) ? 16 * 128 : 16 * (pass * 16 + 17) + 15;
    for (;;) {
      int p = 0x7FFFFFFF;
      if (tid < 16) {
        const int* pa = gcnt + tid * 64;
        asm volatile("global_load_dword %0, %1, off sc1\n\ts_waitcnt vmcnt(0)"
                     : "=v"(p) : "v"(pa) : "memory");
      }
      if (__syncthreads_and(p >= thr)) break;
      __builtin_amdgcn_s_sleep(32);
    }

    const int m0 = pass * 256 + wave * 64;
    const unsigned short* hp = hseq + (size_t)(m0 + ln) * Hh + hi * 8;
    f32x4 acc[4][4];
#pragma unroll
    for (int mi = 0; mi < 4; ++mi)
#pragma unroll
      for (int ni = 0; ni < 4; ++ni) acc[mi][ni] = (f32x4)0.f;

    for (int half = 0; half < 2; ++half) {
      __syncthreads();   // prior W_lds readers done
#pragma unroll
      for (int c = 0; c < 8; ++c) {
        int f = c * 256 + tid;          // chunk = kc_local*64 + row
        int row = f & 63;
        int kc = (f >> 6) + half * 32;  // global kc
        short8 v;
        if (BF16W) {
          v = *(const short8*)(Wbf + (size_t)(n0 + row) * Hh + kc * 8);
        } else {
          const float* q = Wf + (size_t)(n0 + row) * Hh + kc * 8;
          short8 tv;
#pragma unroll
          for (int e = 0; e < 8; ++e) tv[e] = (short)f2bf(q[e]);
          v = tv;
        }
        *(short8*)&W_lds[f * 8] = v;
      }
      __syncthreads();
      for (int kt = half * 8; kt < half * 8 + 8; ++kt) {
        short8 aW[4], bH[4];
#pragma unroll
        for (int ni = 0; ni < 4; ++ni)
          aW[ni] = *(const short8*)
              &W_lds[((((kt - half * 8) * 4 + hi) * 64) + ni * 16 + ln) * 8];
#pragma unroll
        for (int mi = 0; mi < 4; ++mi)
          bH[mi] = *(const short8*)(hp + (size_t)mi * 16 * Hh + kt * 32);
#pragma unroll
        for (int mi = 0; mi < 4; ++mi)
#pragma unroll
          for (int ni = 0; ni < 4; ++ni)
            acc[mi][ni] = __builtin_amdgcn_mfma_f32_16x16x32_bf16(aW[ni], bH[mi], acc[mi][ni], 0, 0, 0);
      }
    }

#pragma unroll
    for (int ni = 0; ni < 4; ++ni) {
      const int n = n0 + ni * 16 + hi * 4;
#pragma unroll
      for (int mi = 0; mi < 4; ++mi) {
        int m = m0 + mi * 16 + ln;
        if (m < 2032) {
          int t = m >> 4, bb = m & 15;
          float* dst = out + ((size_t)(bb * Tt + 1 + t)) * Vv + n;
          f32x4 o = acc[mi][ni] + bv[ni];
          __builtin_nontemporal_store(o, (f32x4*)dst);
        }
      }
    }
  }
}

// ---------------- fused dec kernel: scan + gated logits ----------------
template <bool BF16W>
__global__ void __launch_bounds__(256) k_dec_logits(
    const float* __restrict__ Whh, const float* __restrict__ bhh,
    const float* __restrict__ gx_d, uint2* __restrict__ pairs,
    unsigned short* __restrict__ hseq, int* __restrict__ gcnt,
    const unsigned short* __restrict__ Wbf, const float* __restrict__ Wf,
    const float* __restrict__ bias, float* __restrict__ out) {
  __shared__ short smem[16384];   // 32 KB: scan h_lds (2KB) / logits W tile
  if (blockIdx.x < NSW)
    scan_body<true>(Whh, bhh, gx_d, pairs, hseq, Tt - 1, (float*)smem, gcnt);
  else
    logits_gated<BF16W>(blockIdx.x - NSW, hseq, Wbf, Wf, bias, gcnt, out, smem);
}

// ---------------- fused z + hid0 (per-batch) ----------------
__global__ void k_zh(const uint2* __restrict__ hp,
                     const float* __restrict__ Wz, const float* __restrict__ bz,
                     float* __restrict__ zout,
                     const float* __restrict__ Wh, const float* __restrict__ bh,
                     uint2* __restrict__ hp0) {
  int b = blockIdx.x;
  int tid = threadIdx.x;  // 512
  __shared__ float hsh[Hh];
  __shared__ float zsh[Ll];
  hsh[tid] = __uint_as_float(hp[b * Hh + tid].x);
  __syncthreads();
  if (tid < Ll) {
    float acc = bz[tid];
#pragma unroll 4
    for (int k = 0; k < Hh; k++) acc = fmaf(hsh[k], Wz[(size_t)tid * Hh + k], acc);
    zsh[tid] = acc;
    zout[b * Ll + tid] = acc;
  }
  __syncthreads();
  float acc = bh[tid];
#pragma unroll 4
  for (int l = 0; l < Ll; l++) acc = fmaf(zsh[l], Wh[(size_t)tid * Ll + l], acc);
  hp0[b * Hh + tid] = make_uint2(__float_as_uint(tanhf(acc)), 0u);
}

extern "C" void kernel_launch(void* const* d_in, const int* in_sizes, int n_in,
                              void* d_out, int out_size, void* d_ws, size_t ws_size,
                              hipStream_t stream) {
  const int* x = (const int*)d_in[0];
  const float* enc_emb = (const float*)d_in[1];
  const float* enc_Wih = (const float*)d_in[2];
  const float* enc_bih = (const float*)d_in[3];
  const float* enc_Whh = (const float*)d_in[4];
  const float* enc_bhh = (const float*)d_in[5];
  const float* fc_enc_W = (const float*)d_in[6];
  const float* fc_enc_b = (const float*)d_in[7];
  const float* fc_dec_W = (const float*)d_in[8];
  const float* fc_dec_b = (const float*)d_in[9];
  const float* dec_emb = (const float*)d_in[10];
  const float* dec_Wih = (const float*)d_in[11];
  const float* dec_bih = (const float*)d_in[12];
  const float* dec_Whh = (const float*)d_in[13];
  const float* dec_bhh = (const float*)d_in[14];
  const float* dec_fcW = (const float*)d_in[15];
  const float* dec_fcb = (const float*)d_in[16];
  float* out = (float*)d_out;

  float* ws = (float*)d_ws;
  size_t off = 0;
  float* wihT_e = ws + off; off += 393216;
  float* wihT_d = ws + off; off += 393216;
  float* gx_e = ws + off; off += 3145728;
  float* gx_d = ws + off; off += 3121152;
  uint2* enc_pairs = (uint2*)(ws + off); off += 4 * NPAIRB;
  uint2* dec_pairs = (uint2*)(ws + off); off += 4 * NPAIRB;
  int* gcnt = (int*)(ws + off); off += 1024;          // 16 lines x 64 ints
  unsigned short* hseq_bf = (unsigned short*)(ws + off); off += 524288;
  size_t wbf_elems = (size_t)Vv * Hh;
  bool use_wbf = (off + wbf_elems / 2) * sizeof(float) <= ws_size;
  unsigned short* wbf = (unsigned short*)(ws + off);

  // one prep kernel: cvt + out-row0 zero + pair zero + gcnt zero + both transposes
  int ncvt = use_wbf ? (int)(wbf_elems / 4 / 256) : 0;
  k_prep<<<ncvt + 2000 + 64 + 1 + 768, 256, 0, stream>>>(
      dec_fcW, wbf, ncvt, out, enc_pairs, gcnt, enc_Wih, wihT_e, dec_Wih, wihT_d);

  // gx_e (decoder gx fused into the encoder-scan launch)
  k_gx<<<128 * 6, 256, 0, stream>>>(x, enc_emb, wihT_e, enc_bih, gx_e);

  // encoder scan (256 WGs, 16 groups) + gx_d (762 WGs)
  k_enc_fused<<<NSW + 762, 256, 0, stream>>>(enc_Whh, enc_bhh, gx_e, enc_pairs,
                                             x, dec_emb, wihT_d, dec_bih, gx_d);

  // z (output 2) + hid0 -> dec pairs buf0
  k_zh<<<16, 512, 0, stream>>>(enc_pairs, fc_enc_W, fc_enc_b,
                               out + (size_t)Bb * Tt * Vv, fc_dec_W, fc_dec_b, dec_pairs);

  // decoder scan + gated logits (overlapped)
  if (use_wbf)
    k_dec_logits<true><<<NSW + NLOG, 256, 0, stream>>>(
        dec_Whh, dec_bhh, gx_d, dec_pairs, hseq_bf, gcnt, wbf, dec_fcW, dec_fcb, out);
  else
    k_dec_logits<false><<<NSW + NLOG, 256, 0, stream>>>(
        dec_Whh, dec_bhh, gx_d, dec_pairs, hseq_bf, gcnt,
        (unsigned short*)nullptr, dec_fcW, dec_fcb, out);
}

// Round 24
// 689.286 us; speedup vs baseline: 1.1205x; 1.1205x over previous
//
#include <hip/hip_runtime.h>

#define Vv 32000
#define Ee 256
#define Hh 512
#define Ll 128
#define Bb 16
#define Tt 128
#define G3 1536   // 3*H
#define NSW 256   // scan WGs: 16 groups x 16 WGs
#define NPAIRB (Bb * Hh)  // pairs per buffer

typedef __attribute__((ext_vector_type(8))) short short8;
typedef __attribute__((ext_vector_type(4))) float f32x4;

__device__ __forceinline__ float sigmoidf_(float x) { return 1.f / (1.f + __expf(-x)); }

__device__ __forceinline__ unsigned short f2bf(float f) {
  unsigned int u = __float_as_uint(f);
  u = (u + 0x7fffu + ((u >> 16) & 1u)) >> 16;
  return (unsigned short)u;
}

// ---------------- prep kernel: cvt + zero_first + pair-zero + 2 transposes ----------------
__device__ __forceinline__ void transpose_body(int b, const float* __restrict__ in,
                                               float* __restrict__ outp) {
  __shared__ float tile[32][33];
  int bx = b & 7, by = b >> 3;           // grid (8, 48) flattened
  int tx = threadIdx.x & 31, ty = threadIdx.x >> 5;
  int c = bx * 32 + tx;
  int r0 = by * 32;
  for (int i = ty; i < 32; i += 8)
    tile[i][tx] = in[(size_t)(r0 + i) * 256 + c];
  __syncthreads();
  int r = r0 + tx;
  int c0 = bx * 32;
  for (int i = ty; i < 32; i += 8)
    outp[(size_t)(c0 + i) * 1536 + r] = tile[tx][i];
}

__global__ void __launch_bounds__(256) k_prep(
    const float* __restrict__ cvt_in, unsigned short* __restrict__ cvt_out, int ncvt,
    float* __restrict__ out, uint2* __restrict__ pairs0,
    const float* __restrict__ encWih, float* __restrict__ wihT_e,
    const float* __restrict__ decWih, float* __restrict__ wihT_d) {
  int bid = blockIdx.x;
  const int tid = threadIdx.x;
  if (bid < ncvt) {
    int i = bid * 256 + tid;
    float4 v = ((const float4*)cvt_in)[i];
    ushort4 o;
    o.x = f2bf(v.x); o.y = f2bf(v.y); o.z = f2bf(v.z); o.w = f2bf(v.w);
    ((ushort4*)cvt_out)[i] = o;
    return;
  }
  bid -= ncvt;
  if (bid < 2000) {              // zero out[:,0,:]  (2000*256 = 512000 = Bb*Vv)
    int idx = bid * 256 + tid;
    int b = idx / Vv, v = idx % Vv;
    out[(size_t)b * Tt * Vv + v] = 0.f;
    return;
  }
  bid -= 2000;
  if (bid < 64) {                // zero 256 KB of pair buffers (epochs+values)
    uint4 z = make_uint4(0u, 0u, 0u, 0u);
    ((uint4*)pairs0)[bid * 256 + tid] = z;
    return;
  }
  bid -= 64;
  if (bid < 384) transpose_body(bid, encWih, wihT_e);
  else transpose_body(bid - 384, decWih, wihT_d);
}

// ---------------- gx body ----------------
__device__ __forceinline__ void gx_body(int e, const int* __restrict__ x,
                                        const float* __restrict__ emb,
                                        const float* __restrict__ WihT,
                                        const float* __restrict__ b_ih,
                                        float* __restrict__ gx) {
  __shared__ float A[16][Ee];
  int mt = e / 6, gy = e % 6;
  int g = gy * 256 + threadIdx.x;
  for (int i = 0; i < 16; i++) {
    int tok = x[i * Tt + mt];
    A[i][threadIdx.x] = emb[(size_t)tok * Ee + threadIdx.x];
  }
  __syncthreads();
  float acc[16];
  float bg = b_ih[g];
#pragma unroll
  for (int i = 0; i < 16; i++) acc[i] = bg;
#pragma unroll 4
  for (int ee = 0; ee < Ee; ee++) {
    float w = WihT[(size_t)ee * G3 + g];
#pragma unroll
    for (int i = 0; i < 16; i++) acc[i] = fmaf(A[i][ee], w, acc[i]);
  }
#pragma unroll
  for (int i = 0; i < 16; i++)
    gx[(size_t)(mt * 16 + i) * G3 + g] = acc[i];
}

__global__ void k_gx(const int* __restrict__ x, const float* __restrict__ emb,
                     const float* __restrict__ WihT, const float* __restrict__ b_ih,
                     float* __restrict__ gx) {
  gx_body(blockIdx.x, x, emb, WihT, b_ih, gx);
}

// ---------------- scan body: data-is-flag pair exchange (r14 proven) ----------------
template <bool HSEQ>
__device__ __forceinline__ void scan_body(
    const float* __restrict__ Whh, const float* __restrict__ bhh,
    const float* __restrict__ gx, uint2* __restrict__ pairs,
    unsigned short* __restrict__ hseq, int nsteps) {
  __shared__ float h_lds[Hh];   // this group's batch h
  const int tid = threadIdx.x;
  const int wg = blockIdx.x;
  const int g = wg >> 4;
  const int wgl = wg & 15;
  const int wave = tid >> 6;
  const int lane = tid & 63;
  const int cl = lane >> 3;    // 0..7
  const int ks = lane & 7;     // 0..7
  const int j = wgl * 32 + wave * 8 + cl;
  const bool gate = (ks == 0);

  // weights: 3 gates x 64 interleaved k in f32 regs
  float wr[64], wz[64], wn[64];
  {
    const float* R = Whh + (size_t)j * Hh + ks * 4;
    const float* Z = R + (size_t)Hh * Hh;
    const float* N = Z + (size_t)Hh * Hh;
#pragma unroll
    for (int q = 0; q < 16; ++q) {
      float4 a = *(const float4*)(R + q * 32);
      float4 b = *(const float4*)(Z + q * 32);
      float4 c = *(const float4*)(N + q * 32);
      wr[4*q] = a.x; wr[4*q+1] = a.y; wr[4*q+2] = a.z; wr[4*q+3] = a.w;
      wz[4*q] = b.x; wz[4*q+1] = b.y; wz[4*q+2] = b.z; wz[4*q+3] = b.w;
      wn[4*q] = c.x; wn[4*q+1] = c.y; wn[4*q+2] = c.z; wn[4*q+3] = c.w;
    }
  }
  float bhr = 0.f, bhz = 0.f, bhn = 0.f;
  if (gate) { bhr = bhh[j]; bhz = bhh[Hh + j]; bhn = bhh[2 * Hh + j]; }

  float xr = 0.f, xz = 0.f, xn = 0.f;
  if (gate) {
    const float* gp = gx + (size_t)g * G3 + j;
    xr = gp[0]; xz = gp[Hh]; xn = gp[2 * Hh];
  }

  for (int t = 0; t < nsteps; ++t) {
    // ---- poll + stage h(t): data IS the flag (one LLC RT) ----
    {
      const uint4* pp =
          (const uint4*)(pairs + (size_t)(t & 1) * NPAIRB + (size_t)g * Hh) + tid;
      const unsigned ep = (unsigned)t;
      uint4 v;
      for (int it = 0; it < 200000; ++it) {
        asm volatile("global_load_dwordx4 %0, %1, off sc1\n\ts_waitcnt vmcnt(0)"
                     : "=v"(v) : "v"(pp) : "memory");
        if (v.y == ep && v.w == ep) break;
      }
      *(float2*)&h_lds[2 * tid] =
          make_float2(__uint_as_float(v.x), __uint_as_float(v.z));
    }
    __syncthreads();

    // ---- per-lane partial dots (reg weights x LDS h broadcast) ----
    float aR = 0.f, aZ = 0.f, aN = 0.f;
    {
      const float* hb = h_lds + ks * 4;
#pragma unroll
      for (int q = 0; q < 16; ++q) {
        float4 hv = *(const float4*)(hb + q * 32);
        aR = fmaf(wr[4*q+0], hv.x, aR);
        aR = fmaf(wr[4*q+1], hv.y, aR);
        aR = fmaf(wr[4*q+2], hv.z, aR);
        aR = fmaf(wr[4*q+3], hv.w, aR);
        aZ = fmaf(wz[4*q+0], hv.x, aZ);
        aZ = fmaf(wz[4*q+1], hv.y, aZ);
        aZ = fmaf(wz[4*q+2], hv.z, aZ);
        aZ = fmaf(wz[4*q+3], hv.w, aZ);
        aN = fmaf(wn[4*q+0], hv.x, aN);
        aN = fmaf(wn[4*q+1], hv.y, aN);
        aN = fmaf(wn[4*q+2], hv.z, aN);
        aN = fmaf(wn[4*q+3], hv.w, aN);
      }
    }
    aR += __shfl_xor(aR, 1, 64); aR += __shfl_xor(aR, 2, 64); aR += __shfl_xor(aR, 4, 64);
    aZ += __shfl_xor(aZ, 1, 64); aZ += __shfl_xor(aZ, 2, 64); aZ += __shfl_xor(aZ, 4, 64);
    aN += __shfl_xor(aN, 1, 64); aN += __shfl_xor(aN, 2, 64); aN += __shfl_xor(aN, 4, 64);

    if (gate) {
      float r = sigmoidf_(xr + aR + bhr);
      float u = sigmoidf_(xz + aZ + bhz);
      float n = tanhf(xn + r * (aN + bhn));
      float hold = h_lds[j];
      float hnew = (1.f - u) * n + u * hold;
      uint2 pv = make_uint2(__float_as_uint(hnew), (unsigned)(t + 1));
      uint2* dst = pairs + (size_t)((t + 1) & 1) * NPAIRB + (size_t)g * Hh + j;
      asm volatile("global_store_dwordx2 %0, %1, off sc1" : : "v"(dst), "v"(pv) : "memory");
      if (HSEQ) hseq[((size_t)t * Bb + g) * Hh + j] = f2bf(hnew);
      if (t + 1 < nsteps) {
        const float* gp = gx + (size_t)((t + 1) * Bb + g) * G3 + j;
        xr = gp[0]; xz = gp[Hh]; xn = gp[2 * Hh];
      }
    }
    __syncthreads();   // protect h_lds before next staging overwrite
  }
}

// ---------------- fused enc kernel: scan + decoder gx ----------------
__global__ void __launch_bounds__(256, 1) k_enc_fused(
    const float* __restrict__ Whh, const float* __restrict__ bhh,
    const float* __restrict__ gx_e, uint2* __restrict__ pairs,
    const int* __restrict__ x, const float* __restrict__ dec_emb,
    const float* __restrict__ wihT_d, const float* __restrict__ dec_bih,
    float* __restrict__ gx_d) {
  if (blockIdx.x < NSW)
    scan_body<false>(Whh, bhh, gx_e, pairs, (unsigned short*)nullptr, Tt);
  else
    gx_body(blockIdx.x - NSW, x, dec_emb, wihT_d, dec_bih, gx_d);
}

// ---------------- standalone decoder scan ----------------
__global__ void __launch_bounds__(256, 1) k_dec_scan(
    const float* __restrict__ Whh, const float* __restrict__ bhh,
    const float* __restrict__ gx_d, uint2* __restrict__ pairs,
    unsigned short* __restrict__ hseq) {
  scan_body<true>(Whh, bhh, gx_d, pairs, hseq, Tt - 1);
}

// ---------------- fused z + hid0 (per-batch) ----------------
__global__ void k_zh(const uint2* __restrict__ hp,
                     const float* __restrict__ Wz, const float* __restrict__ bz,
                     float* __restrict__ zout,
                     const float* __restrict__ Wh, const float* __restrict__ bh,
                     uint2* __restrict__ hp0) {
  int b = blockIdx.x;
  int tid = threadIdx.x;  // 512
  __shared__ float hsh[Hh];
  __shared__ float zsh[Ll];
  hsh[tid] = __uint_as_float(hp[b * Hh + tid].x);
  __syncthreads();
  if (tid < Ll) {
    float acc = bz[tid];
#pragma unroll 4
    for (int k = 0; k < Hh; k++) acc = fmaf(hsh[k], Wz[(size_t)tid * Hh + k], acc);
    zsh[tid] = acc;
    zout[b * Ll + tid] = acc;
  }
  __syncthreads();
  float acc = bh[tid];
#pragma unroll 4
  for (int l = 0; l < Ll; l++) acc = fmaf(zsh[l], Wh[(size_t)tid * Ll + l], acc);
  hp0[b * Hh + tid] = make_uint2(__float_as_uint(tanhf(acc)), 0u);
}

// ---------------- logits: W-stationary MFMA, 64-col tiles, nt stores, mi-outer ----------
template <bool BF16W>
__global__ void __launch_bounds__(512, 1) k_logits_mfma(
    const unsigned short* __restrict__ Abf,  // hs [2048][512] bf16
    const unsigned short* __restrict__ Wbf,  // [32000][512] bf16 (if BF16W)
    const float* __restrict__ Wf,            // [32000][512] f32 (fallback)
    const float* __restrict__ bias, float* __restrict__ out) {
  __shared__ short W_lds[32768];  // 64 KB, frag-order
  const int tid = threadIdx.x;
  const int wave = tid >> 6, lane = tid & 63;
  const int ln = lane & 15, hi = lane >> 4;
  const int n0 = blockIdx.x * 64;

  // ---- stage W tile into LDS (frag order) ----
#pragma unroll
  for (int c = 0; c < 8; ++c) {
    int f = c * 512 + tid;       // chunk id = kc*64 + row
    int row = f & 63;
    int kc = f >> 6;             // 0..63
    short8 v;
    if (BF16W) {
      v = *(const short8*)(Wbf + (size_t)(n0 + row) * Hh + kc * 8);
    } else {
      const float* q = Wf + (size_t)(n0 + row) * Hh + kc * 8;
      short8 tv;
#pragma unroll
      for (int e = 0; e < 8; ++e) tv[e] = (short)f2bf(q[e]);
      v = tv;
    }
    *(short8*)&W_lds[f * 8] = v;
  }
  __syncthreads();

  f32x4 bv[4];
#pragma unroll
  for (int ni = 0; ni < 4; ++ni)
    bv[ni] = *(const f32x4*)&bias[n0 + ni * 16 + hi * 4];

  for (int pass = 0; pass < 4; ++pass) {
    const int m0 = pass * 512 + wave * 64;
    const unsigned short* hp = Abf + (size_t)(m0 + ln) * Hh + hi * 8;
    f32x4 acc[4][4];  // [mi][ni]
#pragma unroll
    for (int mi = 0; mi < 4; ++mi)
#pragma unroll
      for (int ni = 0; ni < 4; ++ni) acc[mi][ni] = (f32x4)0.f;

    for (int kt = 0; kt < 16; ++kt) {
      short8 aW[4], bH[4];
#pragma unroll
      for (int ni = 0; ni < 4; ++ni)
        aW[ni] = *(const short8*)&W_lds[(((kt * 4 + hi) * 64) + ni * 16 + ln) * 8];
#pragma unroll
      for (int mi = 0; mi < 4; ++mi)
        bH[mi] = *(const short8*)(hp + (size_t)mi * 16 * Hh + kt * 32);
#pragma unroll
      for (int mi = 0; mi < 4; ++mi)
#pragma unroll
        for (int ni = 0; ni < 4; ++ni)
          acc[mi][ni] = __builtin_amdgcn_mfma_f32_16x16x32_bf16(aW[ni], bH[mi], acc[mi][ni], 0, 0, 0);
    }

#pragma unroll
    for (int mi = 0; mi < 4; ++mi) {
      int m = m0 + mi * 16 + ln;
      if (m < 2032) {
        int t = m >> 4, bb = m & 15;
        float* rowp = out + ((size_t)(bb * Tt + 1 + t)) * Vv;
#pragma unroll
        for (int ni = 0; ni < 4; ++ni) {
          const int n = n0 + ni * 16 + hi * 4;
          f32x4 o = acc[mi][ni] + bv[ni];
          __builtin_nontemporal_store(o, (f32x4*)(rowp + n));
        }
      }
    }
  }
}

extern "C" void kernel_launch(void* const* d_in, const int* in_sizes, int n_in,
                              void* d_out, int out_size, void* d_ws, size_t ws_size,
                              hipStream_t stream) {
  const int* x = (const int*)d_in[0];
  const float* enc_emb = (const float*)d_in[1];
  const float* enc_Wih = (const float*)d_in[2];
  const float* enc_bih = (const float*)d_in[3];
  const float* enc_Whh = (const float*)d_in[4];
  const float* enc_bhh = (const float*)d_in[5];
  const float* fc_enc_W = (const float*)d_in[6];
  const float* fc_enc_b = (const float*)d_in[7];
  const float* fc_dec_W = (const float*)d_in[8];
  const float* fc_dec_b = (const float*)d_in[9];
  const float* dec_emb = (const float*)d_in[10];
  const float* dec_Wih = (const float*)d_in[11];
  const float* dec_bih = (const float*)d_in[12];
  const float* dec_Whh = (const float*)d_in[13];
  const float* dec_bhh = (const float*)d_in[14];
  const float* dec_fcW = (const float*)d_in[15];
  const float* dec_fcb = (const float*)d_in[16];
  float* out = (float*)d_out;

  float* ws = (float*)d_ws;
  size_t off = 0;
  float* wihT_e = ws + off; off += 393216;
  float* wihT_d = ws + off; off += 393216;
  float* gx_e = ws + off; off += 3145728;
  float* gx_d = ws + off; off += 3121152;
  uint2* enc_pairs = (uint2*)(ws + off); off += 4 * NPAIRB;
  uint2* dec_pairs = (uint2*)(ws + off); off += 4 * NPAIRB;
  unsigned short* hseq_bf = (unsigned short*)(ws + off); off += 524288;
  size_t wbf_elems = (size_t)Vv * Hh;
  bool use_wbf = (off + wbf_elems / 2) * sizeof(float) <= ws_size;
  unsigned short* wbf = (unsigned short*)(ws + off);

  // one prep kernel: cvt + out-row0 zero + pair-buffer zero + both Wih transposes
  int ncvt = use_wbf ? (int)(wbf_elems / 4 / 256) : 0;   // 16000 when enabled
  k_prep<<<ncvt + 2000 + 64 + 768, 256, 0, stream>>>(
      dec_fcW, wbf, ncvt, out, enc_pairs, enc_Wih, wihT_e, dec_Wih, wihT_d);

  // gx_e (decoder gx fused into the encoder-scan launch)
  k_gx<<<128 * 6, 256, 0, stream>>>(x, enc_emb, wihT_e, enc_bih, gx_e);

  // encoder scan (256 WGs, 16 groups) + gx_d (762 WGs)
  k_enc_fused<<<NSW + 762, 256, 0, stream>>>(enc_Whh, enc_bhh, gx_e, enc_pairs,
                                             x, dec_emb, wihT_d, dec_bih, gx_d);

  // z (output 2) + hid0 -> dec pairs buf0
  k_zh<<<16, 512, 0, stream>>>(enc_pairs, fc_enc_W, fc_enc_b,
                               out + (size_t)Bb * Tt * Vv, fc_dec_W, fc_dec_b, dec_pairs);

  // decoder scan
  k_dec_scan<<<NSW, 256, 0, stream>>>(dec_Whh, dec_bhh, gx_d, dec_pairs, hseq_bf);

  // logits (W-stationary, 500 WGs x 512 thr, 64-col tiles, nt stores)
  if (use_wbf)
    k_logits_mfma<true><<<500, 512, 0, stream>>>(hseq_bf, wbf, dec_fcW, dec_fcb, out);
  else
    k_logits_mfma<false><<<500, 512, 0, stream>>>(hseq_bf, (unsigned short*)nullptr,
                                                  dec_fcW, dec_fcb, out);
}